// Round 8
// baseline (93.662 us; speedup 1.0000x reference)
//
#include <hip/hip_runtime.h>

// B=2, S=2048, D=1024, H=16, HD=64. K == Q (xk = x@Wq.T, same RoPE).
// Pipeline: fused f32->bf16 convert -> merged GEMM (XCD-chunked):
//   [x@Wq.T + RoPE -> Kf frag-layout], [x@Wv.T -> Vf frag-layout]
// -> flash attention, no LDS/barriers in main loop, frag loads coalesced.
// R8: attn waves own 64 q-rows (4 qs, two groups of 2) -> K/V L2 traffic
//     halved (540->278 MB); gemm blocks XCD-chunked by bm (A-panel reuse).

typedef float f32x4 __attribute__((ext_vector_type(4)));
typedef short s16x8 __attribute__((ext_vector_type(8)));

__device__ inline unsigned short f2bf(float f) {
  union { float f; unsigned u; } v; v.f = f;
  unsigned r = v.u + 0x7FFFu + ((v.u >> 16) & 1u);
  return (unsigned short)(r >> 16);
}

__device__ inline void gload16(const unsigned short* g, unsigned short* l) {
  __builtin_amdgcn_global_load_lds(
      (const __attribute__((address_space(1))) unsigned int*)g,
      (__attribute__((address_space(3))) unsigned int*)l, 16, 0, 0);
}

__global__ __launch_bounds__(256) void convert_all(
    const float* __restrict__ x, const float* __restrict__ wq,
    const float* __restrict__ wv, unsigned short* __restrict__ xb,
    unsigned short* __restrict__ wqb, unsigned short* __restrict__ wvb) {
  int i = blockIdx.x * 256 + threadIdx.x;
  const float* src; unsigned short* dst; int off;
  if (i < 1048576) { src = x; dst = xb; off = i; }
  else if (i < 1310720) { src = wq; dst = wqb; off = i - 1048576; }
  else { src = wv; dst = wvb; off = i - 1310720; }
  float4 v = ((const float4*)src)[off];
  ushort4 o;
  o.x = f2bf(v.x); o.y = f2bf(v.y); o.z = f2bf(v.z); o.w = f2bf(v.w);
  ((ushort4*)dst)[off] = o;
}

// Merged GEMM, grid 512, XCD-chunked: XCD x owns bm in [4x,4x+4) for both
// projections -> A-panel (1MB) + W tiles L2-resident per XCD.
__global__ __launch_bounds__(256, 2) void qv_gemm(
    const unsigned short* __restrict__ A, const unsigned short* __restrict__ Wq,
    const unsigned short* __restrict__ Wv, const float* __restrict__ cosT,
    const float* __restrict__ sinT, unsigned short* __restrict__ Kf,
    unsigned short* __restrict__ Vf) {
  __shared__ unsigned short GS[2][2][128][64];  // [buf][A/B][row][col] 64KB
  int tid = threadIdx.x;
  int fid = blockIdx.x;
  int xcd = fid & 7, idx = fid >> 3;
  int isq = idx & 1;
  int bn = (idx >> 1) & 7;
  int bm = xcd * 4 + (idx >> 4);
  int w = tid >> 6, lane = tid & 63, lr = lane & 15, lg = lane >> 4;
  int wm = w >> 1, wn = w & 1;
  int l8 = lane >> 3, l7 = lane & 7;
  f32x4 acc[4][4] = {};

  const unsigned short* Wp = isq ? Wq : Wv;
  const unsigned short* srcbase =
      (w < 2) ? (A + bm * 128 * 1024) : (Wp + bn * 128 * 1024);
  int ab = w >> 1;

  auto stage = [&](int step) {
    int buf = step & 1, kt = step * 64;
#pragma unroll
    for (int i = 0; i < 8; ++i) {
      int rgrp = (w & 1) * 8 + i;
      int u = rgrp * 8 + l8;
      int ch = l7 ^ (u & 7);
      gload16(srcbase + u * 1024 + kt + ch * 8,
              (unsigned short*)&GS[buf][ab][rgrp * 8][0]);
    }
  };

  stage(0);
  for (int step = 0; step < 16; ++step) {
    int buf = step & 1;
    asm volatile("s_waitcnt vmcnt(0)" ::: "memory");
    __syncthreads();
    if (step + 1 < 16) stage(step + 1);
    s16x8 af[4][2], bfr[4][2];
#pragma unroll
    for (int mf = 0; mf < 4; ++mf)
#pragma unroll
      for (int kk = 0; kk < 2; ++kk)
        af[mf][kk] = *(const s16x8*)
            &GS[buf][0][wm * 64 + mf * 16 + lr][((kk * 4 + lg) ^ (lr & 7)) * 8];
#pragma unroll
    for (int nf = 0; nf < 4; ++nf)
#pragma unroll
      for (int kk = 0; kk < 2; ++kk)
        bfr[nf][kk] = *(const s16x8*)
            &GS[buf][1][wn * 64 + nf * 16 + lr][((kk * 4 + lg) ^ (lr & 7)) * 8];
#pragma unroll
    for (int mf = 0; mf < 4; ++mf)
#pragma unroll
      for (int nf = 0; nf < 4; ++nf)
#pragma unroll
        for (int kk = 0; kk < 2; ++kk)
          acc[mf][nf] = __builtin_amdgcn_mfma_f32_16x16x32_bf16(
              af[mf][kk], bfr[nf][kk], acc[mf][nf], 0, 0, 0);
  }

  int mBase = bm * 128 + wm * 64;
  int nBase = bn * 128 + wn * 64;
  if (isq) {
    // RoPE, then per-wave LDS transpose -> coalesced dwordx4 Kf stores.
    __syncthreads();
    unsigned short* Lw = &GS[0][0][0][0] + w * (64 * 72);
    int bq = mBase >> 11;
    int sbase = mBase & 2047;
    int kt = sbase >> 6;
    int h = (nBase >> 6);
    int bh = bq * 16 + h;
#pragma unroll
    for (int mf = 0; mf < 4; ++mf)
#pragma unroll
      for (int j = 0; j < 4; ++j) {
        int sp = mf * 16 + 4 * lg + j;
        int s = sbase + sp;
#pragma unroll
        for (int nf = 0; nf < 4; ++nf) {
          int hd = nf * 16 + lr;
          float self = acc[mf][nf][j];
          float part = (nf < 2) ? -acc[mf][nf + 2][j] : acc[mf][nf - 2][j];
          float val = self * cosT[s * 64 + hd] + part * sinT[s * 64 + hd];
          Lw[sp * 72 + hd] = f2bf(val);
        }
      }
    asm volatile("s_waitcnt lgkmcnt(0)" ::: "memory");
    __builtin_amdgcn_sched_barrier(0);
    unsigned short* KfT = Kf + (size_t)(bh * 32 + kt) * 4096;
#pragma unroll
    for (int i = 0; i < 8; ++i) {
      int kk = i & 1, nfk = i >> 1;
      int lg2 = lane >> 4, lr2 = lane & 15;
      int sp = ((nfk >> 1) << 5) | ((lr2 >> 2) << 3) | ((nfk & 1) << 2) |
               (lr2 & 3);
      int c = kk * 4 + lg2;
      s16x8 vch = *(const s16x8*)&Lw[sp * 72 + c * 8];
      *(s16x8*)&KfT[(i * 64 + lane) * 8] = vch;
    }
  } else {
#pragma unroll
    for (int mf = 0; mf < 4; ++mf) {
      int m0 = mBase + mf * 16 + 4 * lg;
      int b = m0 >> 11, s0 = m0 & 2047;
      int kt = s0 >> 6, w0 = s0 & 63;
      int kkv = w0 >> 5, lg2 = (w0 >> 3) & 3, e0 = w0 & 7;
#pragma unroll
      for (int nf = 0; nf < 4; ++nf) {
        int col = nBase + nf * 16 + lr;
        int h = col >> 6;
        int bh = b * 16 + h;
        ushort4 pk;
        pk.x = f2bf(acc[mf][nf][0]); pk.y = f2bf(acc[mf][nf][1]);
        pk.z = f2bf(acc[mf][nf][2]); pk.w = f2bf(acc[mf][nf][3]);
        int idx2 = (((((bh * 32 + kt) * 4 + nf) * 2 + kkv) * 64) +
                    lg2 * 16 + lr) * 8 + e0;
        *(ushort4*)&Vf[idx2] = pk;
      }
    }
  }
}

// Flash attention: block = 128 q-rows, wave = (q-half qh, k-parity par),
// each wave owns 64 q-rows (4 qs in two groups of 2). No LDS/barriers in
// main loop. grid 512: XCD-chunked bh, qb descending (LPT).
__global__ __launch_bounds__(256, 2) void attn(
    const unsigned short* __restrict__ Kf,  // frag layout
    const unsigned short* __restrict__ Vf,  // frag layout
    float* __restrict__ out) {              // [2][2048][1024]
  __shared__ float MB[2][4][4][16][17];
  __shared__ float ML[2][4][2][16];
  const float SC = 0.125f * 1.44269504088896f;  // scale * log2(e)
  const float THR = 44.0f;                      // ~= 8 / SC
  int tid = threadIdx.x;
  int fid = blockIdx.x;
  int bh = 4 * (fid & 7) + ((fid >> 3) & 3);
  int qb = 15 - (fid >> 5);
  int w = tid >> 6, lane = tid & 63, lr = lane & 15, lg = lane >> 4;
  int q0 = qb * 128, qh = w >> 1, par = w & 1;

  const unsigned short* KfB = Kf + (size_t)bh * 32 * 4096;
  const unsigned short* VfB = Vf + (size_t)bh * 32 * 4096;

  // aq (B-operand) gathered from Kf once: 4 qs x 2 kk = 32 VGPR.
  s16x8 aq[4][2];
#pragma unroll
  for (int qs = 0; qs < 4; ++qs) {
    int qr = q0 + qh * 64 + 16 * qs + lr;
    int ktq = qr >> 6, w64 = qr & 63;
    int nfq = ((w64 >> 5) << 1) | ((w64 >> 2) & 1);
    int r31 = w64 & 31;
    int lr2 = ((r31 >> 3) << 2) | (r31 & 3);
#pragma unroll
    for (int kk = 0; kk < 2; ++kk)
      aq[qs][kk] = *(const s16x8*)
          &KfB[((((ktq * 4 + nfq) * 2 + kk) * 64) + lg * 16 + lr2) * 8];
  }

  f32x4 o[4][4] = {};
  float m_[4] = {-1e30f, -1e30f, -1e30f, -1e30f}, l_[4] = {0.f, 0.f, 0.f, 0.f};

  s16x8 kf[4][2], vf[4][2];
  auto loadK = [&](int kt) {
#pragma unroll
    for (int nf = 0; nf < 4; ++nf)
#pragma unroll
      for (int kk = 0; kk < 2; ++kk)
        kf[nf][kk] = *(const s16x8*)
            &KfB[(((kt * 4 + nf) * 2 + kk) * 64 + lane) * 8];
  };
  auto loadV = [&](int kt) {
#pragma unroll
    for (int nf = 0; nf < 4; ++nf)
#pragma unroll
      for (int kk = 0; kk < 2; ++kk)
        vf[nf][kk] = *(const s16x8*)
            &VfB[(((kt * 4 + nf) * 2 + kk) * 64 + lane) * 8];
  };

  // QK^T (swapped) for q-group g (qs = 2g, 2g+1).
  auto qk2 = [&](f32x4 (&sa)[2][4], int g) {
#pragma unroll
    for (int q2 = 0; q2 < 2; ++q2)
#pragma unroll
      for (int nf = 0; nf < 4; ++nf) sa[q2][nf] = (f32x4){0.f, 0.f, 0.f, 0.f};
    __builtin_amdgcn_s_setprio(1);
#pragma unroll
    for (int kk = 0; kk < 2; ++kk)
#pragma unroll
      for (int nf = 0; nf < 4; ++nf)
#pragma unroll
        for (int q2 = 0; q2 < 2; ++q2)
          sa[q2][nf] = __builtin_amdgcn_mfma_f32_16x16x32_bf16(
              kf[nf][kk], aq[2 * g + q2][kk], sa[q2][nf], 0, 0, 0);
    __builtin_amdgcn_s_setprio(0);
  };

  auto mask2 = [&](f32x4 (&sa)[2][4], int g, int kt) {
#pragma unroll
    for (int q2 = 0; q2 < 2; ++q2) {
      int qglob = q0 + qh * 64 + 16 * (2 * g + q2) + lr;
#pragma unroll
      for (int nf = 0; nf < 4; ++nf) {
        int kc = kt * 64 + 8 * lg + 4 * (nf & 1) + 32 * (nf >> 1);
#pragma unroll
        for (int j = 0; j < 4; ++j)
          if (kc + j > qglob) sa[q2][nf][j] = -3e38f;
      }
    }
  };

  // softmax for group g -> packed bf16 P in cpk[2][8].
  auto sm2 = [&](f32x4 (&sa)[2][4], int g, unsigned (&cpk)[2][8]) {
    float tm[2];
    float worst = -3e38f;
#pragma unroll
    for (int q2 = 0; q2 < 2; ++q2) {
      int qs = 2 * g + q2;
      float t = sa[q2][0][0];
#pragma unroll
      for (int nf = 0; nf < 4; ++nf)
#pragma unroll
        for (int j = 0; j < 4; ++j) t = fmaxf(t, sa[q2][nf][j]);
      tm[q2] = t;
      worst = fmaxf(worst, t - m_[qs]);
    }
    if (!__all(worst <= THR)) {  // rare after first tile
#pragma unroll
      for (int q2 = 0; q2 < 2; ++q2) {
        int qs = 2 * g + q2;
        float rm = fmaxf(tm[q2], __shfl_xor(tm[q2], 16));
        rm = fmaxf(rm, __shfl_xor(rm, 32));
        float mn = fmaxf(m_[qs], rm);
        float alpha = exp2f((m_[qs] - mn) * SC);
        m_[qs] = mn; l_[qs] *= alpha;
#pragma unroll
        for (int j = 0; j < 4; ++j) {
          float aj = __shfl(alpha, 4 * lg + j);
#pragma unroll
          for (int nf = 0; nf < 4; ++nf) o[qs][nf][j] *= aj;
        }
      }
    }
#pragma unroll
    for (int q2 = 0; q2 < 2; ++q2) {
      int qs = 2 * g + q2;
      float msc = m_[qs] * SC;
#pragma unroll
      for (int nf = 0; nf < 4; ++nf) {
        float p0 = exp2f(fmaf(sa[q2][nf][0], SC, -msc));
        float p1 = exp2f(fmaf(sa[q2][nf][1], SC, -msc));
        float p2 = exp2f(fmaf(sa[q2][nf][2], SC, -msc));
        float p3 = exp2f(fmaf(sa[q2][nf][3], SC, -msc));
        l_[qs] += (p0 + p1) + (p2 + p3);
        unsigned r0, r1;
        asm("v_cvt_pk_bf16_f32 %0, %1, %2" : "=v"(r0) : "v"(p0), "v"(p1));
        asm("v_cvt_pk_bf16_f32 %0, %1, %2" : "=v"(r1) : "v"(p2), "v"(p3));
        cpk[q2][nf * 2] = r0; cpk[q2][nf * 2 + 1] = r1;
      }
    }
  };

  auto pv2 = [&](unsigned (&cpk)[2][8], int g) {
    __builtin_amdgcn_s_setprio(1);
#pragma unroll
    for (int q2 = 0; q2 < 2; ++q2) {
      int qs = 2 * g + q2;
#pragma unroll
      for (int kk = 0; kk < 2; ++kk) {
        union { unsigned u[4]; s16x8 v; } pa;
        pa.u[0] = cpk[q2][4 * kk + 0]; pa.u[1] = cpk[q2][4 * kk + 1];
        pa.u[2] = cpk[q2][4 * kk + 2]; pa.u[3] = cpk[q2][4 * kk + 3];
#pragma unroll
        for (int nf = 0; nf < 4; ++nf)
          o[qs][nf] = __builtin_amdgcn_mfma_f32_16x16x32_bf16(
              pa.v, vf[nf][kk], o[qs][nf], 0, 0, 0);
      }
    }
    __builtin_amdgcn_s_setprio(0);
  };

  int ktmax = 2 * qb + qh;
  int kt = par;
  bool active = kt <= ktmax;
  if (active) { loadK(kt); loadV(kt); }
  while (active) {
    bool diag = (kt == ktmax);
    f32x4 sa0[2][4], sa1[2][4];
    unsigned cpk0[2][8], cpk1[2][8];
    qk2(sa0, 0);
    if (diag) mask2(sa0, 0, kt);
    sm2(sa0, 0, cpk0);
    qk2(sa1, 1);
    int ktn = kt + 2;
    bool more = ktn <= ktmax;
    if (more) loadK(ktn);  // kf dead; ~450cy ahead of next use
    if (diag) mask2(sa1, 1, kt);
    sm2(sa1, 1, cpk1);
    pv2(cpk0, 0);
    pv2(cpk1, 1);
    if (more) loadV(ktn);  // vf dead; ~600cy ahead of next use
    kt = ktn; active = more;
  }

  // merge: waves (qh,0) and (qh,1) share q-rows; odd writes, even merges.
#pragma unroll
  for (int qs = 0; qs < 4; ++qs) {
    float t = l_[qs];
    t += __shfl_xor(t, 16); t += __shfl_xor(t, 32);
    l_[qs] = t;
  }
  if (par) {
#pragma unroll
    for (int qs = 0; qs < 4; ++qs) {
#pragma unroll
      for (int nf = 0; nf < 4; ++nf)
#pragma unroll
        for (int j = 0; j < 4; ++j)
          MB[qh][qs][nf][4 * lg + j][lr] = o[qs][nf][j];
      if (lg == 0) {
        ML[qh][qs][0][lr] = m_[qs];
        ML[qh][qs][1][lr] = l_[qs];
      }
    }
  }
  __syncthreads();
  if (!par) {
    int b = bh >> 4, h = bh & 15;
#pragma unroll
    for (int qs = 0; qs < 4; ++qs) {
      float m1 = ML[qh][qs][0][lr];
      float l1 = ML[qh][qs][1][lr];
      float ms = fmaxf(m_[qs], m1);
      float a0 = exp2f((m_[qs] - ms) * SC), a1 = exp2f((m1 - ms) * SC);
      float inv = 1.0f / (a0 * l_[qs] + a1 * l1);
#pragma unroll
      for (int j = 0; j < 4; ++j) {
        float c0 = __shfl(a0 * inv, 4 * lg + j);
        float c1 = __shfl(a1 * inv, 4 * lg + j);
#pragma unroll
        for (int nf = 0; nf < 4; ++nf) {
          float o1 = MB[qh][qs][nf][4 * lg + j][lr];
          int q = q0 + qh * 64 + 16 * qs + 4 * lg + j;
          out[(b * 2048 + q) * 1024 + h * 64 + nf * 16 + lr] =
              c0 * o[qs][nf][j] + c1 * o1;
        }
      }
    }
  }
}

extern "C" void kernel_launch(void* const* d_in, const int* in_sizes, int n_in,
                              void* d_out, int out_size, void* d_ws, size_t ws_size,
                              hipStream_t stream) {
  const float* x = (const float*)d_in[0];
  const float* Wq = (const float*)d_in[1];
  const float* Wv = (const float*)d_in[2];
  const float* cosT = (const float*)d_in[3];
  const float* sinT = (const float*)d_in[4];
  float* out = (float*)d_out;

  unsigned short* xb = (unsigned short*)d_ws;        // 4M shorts
  unsigned short* wqb = xb + 4 * 1024 * 1024;        // 1M
  unsigned short* wvb = wqb + 1024 * 1024;           // 1M
  unsigned short* Kfb = wvb + 1024 * 1024;           // 4M (frag-layout RoPE'd Q==K)
  unsigned short* Vfb = Kfb + 4 * 1024 * 1024;       // 4M (frag-layout V)

  convert_all<<<6144, 256, 0, stream>>>(x, Wq, Wv, xb, wqb, wvb);
  qv_gemm<<<512, 256, 0, stream>>>(xb, wqb, wvb, cosT, sinT, Kfb, Vfb);
  attn<<<512, 256, 0, stream>>>(Kfb, Vfb, out);
}

// Round 9
// 74.151 us; speedup vs baseline: 1.2631x; 1.2631x over previous
//
#include <hip/hip_runtime.h>

// B=2, S=2048, D=1024, H=16, HD=64. K == Q (xk = x@Wq.T, same RoPE).
// Pipeline: fused f32->bf16 convert -> merged GEMM (XCD-chunked):
//   [x@Wq.T + RoPE -> Kf frag-layout], [x@Wv.T -> Vf frag-layout]
// -> flash attention, no LDS/barriers in main loop, frag loads coalesced.
// R9: revert attn to 32 q-rows/wave (R7 structure; R8's 64 q-rows spilled:
//     WRITE_SIZE 36MB). Keep gemm XCD-chunking. Add balanced two-round
//     qt pairing (block f with f+512 sums to 31 tiles) + T5 setprio.

typedef float f32x4 __attribute__((ext_vector_type(4)));
typedef short s16x8 __attribute__((ext_vector_type(8)));

__device__ inline unsigned short f2bf(float f) {
  union { float f; unsigned u; } v; v.f = f;
  unsigned r = v.u + 0x7FFFu + ((v.u >> 16) & 1u);
  return (unsigned short)(r >> 16);
}

__device__ inline void gload16(const unsigned short* g, unsigned short* l) {
  __builtin_amdgcn_global_load_lds(
      (const __attribute__((address_space(1))) unsigned int*)g,
      (__attribute__((address_space(3))) unsigned int*)l, 16, 0, 0);
}

__global__ __launch_bounds__(256) void convert_all(
    const float* __restrict__ x, const float* __restrict__ wq,
    const float* __restrict__ wv, unsigned short* __restrict__ xb,
    unsigned short* __restrict__ wqb, unsigned short* __restrict__ wvb) {
  int i = blockIdx.x * 256 + threadIdx.x;
  const float* src; unsigned short* dst; int off;
  if (i < 1048576) { src = x; dst = xb; off = i; }
  else if (i < 1310720) { src = wq; dst = wqb; off = i - 1048576; }
  else { src = wv; dst = wvb; off = i - 1310720; }
  float4 v = ((const float4*)src)[off];
  ushort4 o;
  o.x = f2bf(v.x); o.y = f2bf(v.y); o.z = f2bf(v.z); o.w = f2bf(v.w);
  ((ushort4*)dst)[off] = o;
}

// Merged GEMM, grid 512, XCD-chunked: XCD x owns bm in [4x,4x+4) for both
// projections -> A-panel (1MB) + W tiles L2-resident per XCD.
__global__ __launch_bounds__(256, 2) void qv_gemm(
    const unsigned short* __restrict__ A, const unsigned short* __restrict__ Wq,
    const unsigned short* __restrict__ Wv, const float* __restrict__ cosT,
    const float* __restrict__ sinT, unsigned short* __restrict__ Kf,
    unsigned short* __restrict__ Vf) {
  __shared__ unsigned short GS[2][2][128][64];  // [buf][A/B][row][col] 64KB
  int tid = threadIdx.x;
  int fid = blockIdx.x;
  int xcd = fid & 7, idx = fid >> 3;
  int isq = idx & 1;
  int bn = (idx >> 1) & 7;
  int bm = xcd * 4 + (idx >> 4);
  int w = tid >> 6, lane = tid & 63, lr = lane & 15, lg = lane >> 4;
  int wm = w >> 1, wn = w & 1;
  int l8 = lane >> 3, l7 = lane & 7;
  f32x4 acc[4][4] = {};

  const unsigned short* Wp = isq ? Wq : Wv;
  const unsigned short* srcbase =
      (w < 2) ? (A + bm * 128 * 1024) : (Wp + bn * 128 * 1024);
  int ab = w >> 1;

  auto stage = [&](int step) {
    int buf = step & 1, kt = step * 64;
#pragma unroll
    for (int i = 0; i < 8; ++i) {
      int rgrp = (w & 1) * 8 + i;
      int u = rgrp * 8 + l8;
      int ch = l7 ^ (u & 7);
      gload16(srcbase + u * 1024 + kt + ch * 8,
              (unsigned short*)&GS[buf][ab][rgrp * 8][0]);
    }
  };

  stage(0);
  for (int step = 0; step < 16; ++step) {
    int buf = step & 1;
    asm volatile("s_waitcnt vmcnt(0)" ::: "memory");
    __syncthreads();
    if (step + 1 < 16) stage(step + 1);
    s16x8 af[4][2], bfr[4][2];
#pragma unroll
    for (int mf = 0; mf < 4; ++mf)
#pragma unroll
      for (int kk = 0; kk < 2; ++kk)
        af[mf][kk] = *(const s16x8*)
            &GS[buf][0][wm * 64 + mf * 16 + lr][((kk * 4 + lg) ^ (lr & 7)) * 8];
#pragma unroll
    for (int nf = 0; nf < 4; ++nf)
#pragma unroll
      for (int kk = 0; kk < 2; ++kk)
        bfr[nf][kk] = *(const s16x8*)
            &GS[buf][1][wn * 64 + nf * 16 + lr][((kk * 4 + lg) ^ (lr & 7)) * 8];
#pragma unroll
    for (int mf = 0; mf < 4; ++mf)
#pragma unroll
      for (int nf = 0; nf < 4; ++nf)
#pragma unroll
        for (int kk = 0; kk < 2; ++kk)
          acc[mf][nf] = __builtin_amdgcn_mfma_f32_16x16x32_bf16(
              af[mf][kk], bfr[nf][kk], acc[mf][nf], 0, 0, 0);
  }

  int mBase = bm * 128 + wm * 64;
  int nBase = bn * 128 + wn * 64;
  if (isq) {
    // RoPE, then per-wave LDS transpose -> coalesced dwordx4 Kf stores.
    __syncthreads();
    unsigned short* Lw = &GS[0][0][0][0] + w * (64 * 72);
    int bq = mBase >> 11;
    int sbase = mBase & 2047;
    int kt = sbase >> 6;
    int h = (nBase >> 6);
    int bh = bq * 16 + h;
#pragma unroll
    for (int mf = 0; mf < 4; ++mf)
#pragma unroll
      for (int j = 0; j < 4; ++j) {
        int sp = mf * 16 + 4 * lg + j;
        int s = sbase + sp;
#pragma unroll
        for (int nf = 0; nf < 4; ++nf) {
          int hd = nf * 16 + lr;
          float self = acc[mf][nf][j];
          float part = (nf < 2) ? -acc[mf][nf + 2][j] : acc[mf][nf - 2][j];
          float val = self * cosT[s * 64 + hd] + part * sinT[s * 64 + hd];
          Lw[sp * 72 + hd] = f2bf(val);
        }
      }
    asm volatile("s_waitcnt lgkmcnt(0)" ::: "memory");
    __builtin_amdgcn_sched_barrier(0);
    unsigned short* KfT = Kf + (size_t)(bh * 32 + kt) * 4096;
#pragma unroll
    for (int i = 0; i < 8; ++i) {
      int kk = i & 1, nfk = i >> 1;
      int lg2 = lane >> 4, lr2 = lane & 15;
      int sp = ((nfk >> 1) << 5) | ((lr2 >> 2) << 3) | ((nfk & 1) << 2) |
               (lr2 & 3);
      int c = kk * 4 + lg2;
      s16x8 vch = *(const s16x8*)&Lw[sp * 72 + c * 8];
      *(s16x8*)&KfT[(i * 64 + lane) * 8] = vch;
    }
  } else {
#pragma unroll
    for (int mf = 0; mf < 4; ++mf) {
      int m0 = mBase + mf * 16 + 4 * lg;
      int b = m0 >> 11, s0 = m0 & 2047;
      int kt = s0 >> 6, w0 = s0 & 63;
      int kkv = w0 >> 5, lg2 = (w0 >> 3) & 3, e0 = w0 & 7;
#pragma unroll
      for (int nf = 0; nf < 4; ++nf) {
        int col = nBase + nf * 16 + lr;
        int h = col >> 6;
        int bh = b * 16 + h;
        ushort4 pk;
        pk.x = f2bf(acc[mf][nf][0]); pk.y = f2bf(acc[mf][nf][1]);
        pk.z = f2bf(acc[mf][nf][2]); pk.w = f2bf(acc[mf][nf][3]);
        int idx2 = (((((bh * 32 + kt) * 4 + nf) * 2 + kkv) * 64) +
                    lg2 * 16 + lr) * 8 + e0;
        *(ushort4*)&Vf[idx2] = pk;
      }
    }
  }
}

// Flash attention: no LDS / no barriers in main loop. grid 1024,
// fid -> XCD-chunked bh; qt paired so blocks f and f+512 sum to 31 tiles
// (balanced two-round schedule). 4 waves = (q-half, k-parity).
// Frag loads are coalesced 1KB dwordx4 from Kf/Vf. Pairwise merge via LDS.
__global__ __launch_bounds__(256, 2) void attn(
    const unsigned short* __restrict__ Kf,  // frag layout
    const unsigned short* __restrict__ Vf,  // frag layout
    float* __restrict__ out) {              // [2][2048][1024]
  __shared__ float MB[2][2][4][16][17];
  __shared__ float ML[2][2][2][16];
  const float SC = 0.125f * 1.44269504088896f;  // scale * log2(e)
  const float THR = 44.0f;                      // ~= 8 / SC
  int tid = threadIdx.x;
  int fid = blockIdx.x;
  int bh = 4 * (fid & 7) + ((fid >> 3) & 3);
  int hi = fid >> 5;
  int qt = (hi < 16) ? (31 - hi) : (hi - 16);   // round1: 31..16, round2: 0..15
  int w = tid >> 6, lane = tid & 63, lr = lane & 15, lg = lane >> 4;
  int q0 = qt * 64, qh = w >> 1, par = w & 1;

  const unsigned short* KfB = Kf + (size_t)bh * 32 * 4096;
  const unsigned short* VfB = Vf + (size_t)bh * 32 * 4096;

  // aq (B-operand) gathered from Kf once.
  s16x8 aq[2][2];
#pragma unroll
  for (int qs = 0; qs < 2; ++qs) {
    int qr = q0 + qh * 32 + 16 * qs + lr;
    int ktq = qr >> 6, w64 = qr & 63;
    int nfq = ((w64 >> 5) << 1) | ((w64 >> 2) & 1);
    int r31 = w64 & 31;
    int lr2 = ((r31 >> 3) << 2) | (r31 & 3);
#pragma unroll
    for (int kk = 0; kk < 2; ++kk)
      aq[qs][kk] = *(const s16x8*)
          &KfB[((((ktq * 4 + nfq) * 2 + kk) * 64) + lg * 16 + lr2) * 8];
  }

  f32x4 o[2][4] = {};
  float m_[2] = {-1e30f, -1e30f}, l_[2] = {0.f, 0.f};

  s16x8 kf[4][2], vf[4][2];
  auto loadK = [&](int kt_) {
#pragma unroll
    for (int nf = 0; nf < 4; ++nf)
#pragma unroll
      for (int kk = 0; kk < 2; ++kk)
        kf[nf][kk] = *(const s16x8*)
            &KfB[(((kt_ * 4 + nf) * 2 + kk) * 64 + lane) * 8];
  };
  auto loadV = [&](int kt_) {
#pragma unroll
    for (int nf = 0; nf < 4; ++nf)
#pragma unroll
      for (int kk = 0; kk < 2; ++kk)
        vf[nf][kk] = *(const s16x8*)
            &VfB[(((kt_ * 4 + nf) * 2 + kk) * 64 + lane) * 8];
  };

  int kt = par;
  bool active = kt <= qt;
  if (active) { loadK(kt); loadV(kt); }
  while (active) {
    // QK^T (swapped): sa[qs][nf][j] = S[kcol=kt*64+8lg+j+off(nf)][q0+qh*32+16qs+lr]
    f32x4 sa[2][4];
#pragma unroll
    for (int qs = 0; qs < 2; ++qs)
#pragma unroll
      for (int nf = 0; nf < 4; ++nf) sa[qs][nf] = (f32x4){0.f, 0.f, 0.f, 0.f};
    __builtin_amdgcn_s_setprio(1);
#pragma unroll
    for (int kk = 0; kk < 2; ++kk)
#pragma unroll
      for (int nf = 0; nf < 4; ++nf)
#pragma unroll
        for (int qs = 0; qs < 2; ++qs)
          sa[qs][nf] = __builtin_amdgcn_mfma_f32_16x16x32_bf16(
              kf[nf][kk], aq[qs][kk], sa[qs][nf], 0, 0, 0);
    __builtin_amdgcn_s_setprio(0);

    int ktn = kt + 2;
    bool more = ktn <= qt;
    if (more) loadK(ktn);  // pipelined: lands during softmax+PV

    if (kt == qt) {
#pragma unroll
      for (int qs = 0; qs < 2; ++qs) {
        int qglob = q0 + qh * 32 + 16 * qs + lr;
#pragma unroll
        for (int nf = 0; nf < 4; ++nf) {
          int kc = kt * 64 + 8 * lg + 4 * (nf & 1) + 32 * (nf >> 1);
#pragma unroll
          for (int j = 0; j < 4; ++j)
            if (kc + j > qglob) sa[qs][nf][j] = -3e38f;
        }
      }
    }
    float tm[2];
    float worst = -3e38f;
#pragma unroll
    for (int qs = 0; qs < 2; ++qs) {
      float t = sa[qs][0][0];
#pragma unroll
      for (int nf = 0; nf < 4; ++nf)
#pragma unroll
        for (int j = 0; j < 4; ++j) t = fmaxf(t, sa[qs][nf][j]);
      tm[qs] = t;
      worst = fmaxf(worst, t - m_[qs]);
    }
    if (!__all(worst <= THR)) {  // rare after first tile
#pragma unroll
      for (int qs = 0; qs < 2; ++qs) {
        float rm = fmaxf(tm[qs], __shfl_xor(tm[qs], 16));
        rm = fmaxf(rm, __shfl_xor(rm, 32));
        float mn = fmaxf(m_[qs], rm);
        float alpha = exp2f((m_[qs] - mn) * SC);
        m_[qs] = mn; l_[qs] *= alpha;
#pragma unroll
        for (int j = 0; j < 4; ++j) {
          float aj = __shfl(alpha, 4 * lg + j);
#pragma unroll
          for (int nf = 0; nf < 4; ++nf) o[qs][nf][j] *= aj;
        }
      }
    }
    unsigned cpk[2][8];
#pragma unroll
    for (int qs = 0; qs < 2; ++qs) {
      float msc = m_[qs] * SC;
#pragma unroll
      for (int nf = 0; nf < 4; ++nf) {
        float p0 = exp2f(fmaf(sa[qs][nf][0], SC, -msc));
        float p1 = exp2f(fmaf(sa[qs][nf][1], SC, -msc));
        float p2 = exp2f(fmaf(sa[qs][nf][2], SC, -msc));
        float p3 = exp2f(fmaf(sa[qs][nf][3], SC, -msc));
        l_[qs] += (p0 + p1) + (p2 + p3);
        unsigned r0, r1;
        asm("v_cvt_pk_bf16_f32 %0, %1, %2" : "=v"(r0) : "v"(p0), "v"(p1));
        asm("v_cvt_pk_bf16_f32 %0, %1, %2" : "=v"(r1) : "v"(p2), "v"(p3));
        cpk[qs][nf * 2] = r0; cpk[qs][nf * 2 + 1] = r1;
      }
    }
    s16x8 pav[2][2];
#pragma unroll
    for (int qs = 0; qs < 2; ++qs)
#pragma unroll
      for (int kk = 0; kk < 2; ++kk) {
        union { unsigned u[4]; s16x8 v; } pa;
        pa.u[0] = cpk[qs][4 * kk + 0]; pa.u[1] = cpk[qs][4 * kk + 1];
        pa.u[2] = cpk[qs][4 * kk + 2]; pa.u[3] = cpk[qs][4 * kk + 3];
        pav[qs][kk] = pa.v;
      }
    __builtin_amdgcn_s_setprio(1);
#pragma unroll
    for (int kk = 0; kk < 2; ++kk)
#pragma unroll
      for (int nf = 0; nf < 4; ++nf)
#pragma unroll
        for (int qs = 0; qs < 2; ++qs)
          o[qs][nf] = __builtin_amdgcn_mfma_f32_16x16x32_bf16(
              pav[qs][kk], vf[nf][kk], o[qs][nf], 0, 0, 0);
    __builtin_amdgcn_s_setprio(0);
    if (more) loadV(ktn);  // lands during next QK^T+softmax
    kt = ktn; active = more;
  }

  // pairwise merge: waves (qh,0) and (qh,1) share q-rows; odd writes, even merges
#pragma unroll
  for (int qs = 0; qs < 2; ++qs) {
    float t = l_[qs];
    t += __shfl_xor(t, 16); t += __shfl_xor(t, 32);
    l_[qs] = t;
  }
  if (par) {
#pragma unroll
    for (int qs = 0; qs < 2; ++qs) {
#pragma unroll
      for (int nf = 0; nf < 4; ++nf)
#pragma unroll
        for (int j = 0; j < 4; ++j)
          MB[qh][qs][nf][4 * lg + j][lr] = o[qs][nf][j];
      if (lg == 0) {
        ML[qh][qs][0][lr] = m_[qs];
        ML[qh][qs][1][lr] = l_[qs];
      }
    }
  }
  __syncthreads();
  if (!par) {
    int b = bh >> 4, h = bh & 15;
#pragma unroll
    for (int qs = 0; qs < 2; ++qs) {
      float m1 = ML[qh][qs][0][lr];
      float l1 = ML[qh][qs][1][lr];
      float ms = fmaxf(m_[qs], m1);
      float a0 = exp2f((m_[qs] - ms) * SC), a1 = exp2f((m1 - ms) * SC);
      float inv = 1.0f / (a0 * l_[qs] + a1 * l1);
#pragma unroll
      for (int j = 0; j < 4; ++j) {
        float c0 = __shfl(a0 * inv, 4 * lg + j);
        float c1 = __shfl(a1 * inv, 4 * lg + j);
#pragma unroll
        for (int nf = 0; nf < 4; ++nf) {
          float o1 = MB[qh][qs][nf][4 * lg + j][lr];
          int q = q0 + qh * 32 + 16 * qs + 4 * lg + j;
          out[(b * 2048 + q) * 1024 + h * 64 + nf * 16 + lr] =
              c0 * o[qs][nf][j] + c1 * o1;
        }
      }
    }
  }
}

extern "C" void kernel_launch(void* const* d_in, const int* in_sizes, int n_in,
                              void* d_out, int out_size, void* d_ws, size_t ws_size,
                              hipStream_t stream) {
  const float* x = (const float*)d_in[0];
  const float* Wq = (const float*)d_in[1];
  const float* Wv = (const float*)d_in[2];
  const float* cosT = (const float*)d_in[3];
  const float* sinT = (const float*)d_in[4];
  float* out = (float*)d_out;

  unsigned short* xb = (unsigned short*)d_ws;        // 4M shorts
  unsigned short* wqb = xb + 4 * 1024 * 1024;        // 1M
  unsigned short* wvb = wqb + 1024 * 1024;           // 1M
  unsigned short* Kfb = wvb + 1024 * 1024;           // 4M (frag-layout RoPE'd Q==K)
  unsigned short* Vfb = Kfb + 4 * 1024 * 1024;       // 4M (frag-layout V)

  convert_all<<<6144, 256, 0, stream>>>(x, Wq, Wv, xb, wqb, wvb);
  qv_gemm<<<512, 256, 0, stream>>>(xb, wqb, wvb, cosT, sinT, Kfb, Vfb);
  attn<<<1024, 256, 0, stream>>>(Kfb, Vfb, out);
}